// Round 6
// baseline (1024.669 us; speedup 1.0000x reference)
//
#include <hip/hip_runtime.h>
#include <hip/hip_bf16.h>
#include <math.h>

// ---------------------------------------------------------------------------
// SwinTransformerBlock — plain-bf16 MFMA pipeline, ws_size-ADAPTIVE chunking.
//   B=4 H=W=64 C=768, WS=14, NH=12, HD=64. Hp=Wp=70, 100 windows, T=196.
// Attention in 100/NW window chunks (NW picked from ws_size); per chunk:
//   ln1_win  : LN1 + window partition (chunk rows) -> win_c bf16 [NW*196,768]
//   mgemm<0> : win_c @ wqkvT -> qb/kb [NWb2,196,64], vT [NWb2,64,256] bf16
//   rel      : relh/relw [NWb2,196,14] fp32 bias tables
//   sgemm64<0>: S=qb@kb^T (Ke=64) *0.125 +rel, fused row softmax -> pe bf16
//               [NWb2,196,256] (k-pad cols 196..255 zeroed)
//   sgemm64<1>: outT = vT@pe^T (Ke=256) -> win_c in-place
//   mgemm<1> : win_c @ wprojT +bias, window reverse, + x resid -> OUT (x1 in d_out)
// ln2+MLP in R-row chunks: ln2(out)->y_c; mgemm<2> y_c@wfc1T -> h_c (GELU);
//   mgemm<3> h_c@wfc2T + bias + out resid -> out (in-place RMW).
// Pool: weights [0,14155776) | per-window 2,764,032 B attn chunk | MLP overlay.
// ---------------------------------------------------------------------------

typedef unsigned short u16;
typedef unsigned int u32;
typedef __attribute__((ext_vector_type(8))) short short8;
typedef __attribute__((ext_vector_type(4))) float f32x4;

__device__ __forceinline__ u16 f2bf(float x) {  // RNE f32->bf16
  u32 u = __float_as_uint(x);
  u32 r = (u + 0x7fffu + ((u >> 16) & 1u)) >> 16;
  return (u16)r;
}
__device__ __forceinline__ float bf2f(u16 h) { return __uint_as_float(((u32)h) << 16); }

__device__ __forceinline__ void gl_lds16(const void* g, void* l) {
  __builtin_amdgcn_global_load_lds((const __attribute__((address_space(1))) void*)g,
                                   (__attribute__((address_space(3))) void*)l, 16, 0, 0);
}

__device__ __forceinline__ void block_reduce_2(float& s1, float& s2) {
#pragma unroll
  for (int off = 32; off > 0; off >>= 1) {
    s1 += __shfl_down(s1, off, 64);
    s2 += __shfl_down(s2, off, 64);
  }
  __shared__ float sb[4][2];
  int lane = threadIdx.x & 63;
  int wv = threadIdx.x >> 6;
  if (lane == 0) { sb[wv][0] = s1; sb[wv][1] = s2; }
  __syncthreads();
  s1 = sb[0][0] + sb[1][0] + sb[2][0] + sb[3][0];
  s2 = sb[0][1] + sb[1][1] + sb[2][1] + sb[3][1];
}

// LN1 + window partition (chunk-local out, global decode via tofs).
__global__ __launch_bounds__(256) void ln1_win_kernel(
    const float* __restrict__ x, const float* __restrict__ g,
    const float* __restrict__ bta, u16* __restrict__ wb, int tofs) {
  int token_g = tofs + blockIdx.x;
  int wi = token_g / 196, t = token_g % 196;
  int b = wi / 25, rem = wi % 25;
  int h = (rem / 5) * 14 + t / 14, w = (rem % 5) * 14 + t % 14;
  u16* out = wb + (size_t)blockIdx.x * 768;
  int tid = threadIdx.x;
  if (h >= 64 || w >= 64) {  // zero pad (pad applied AFTER LN in reference)
#pragma unroll
    for (int i = 0; i < 3; i++) out[tid + 256 * i] = 0;
    return;
  }
  const float* xin = x + ((size_t)((b * 64 + h) * 64 + w)) * 768;
  float v[3];
  float s1 = 0.f, s2 = 0.f;
#pragma unroll
  for (int i = 0; i < 3; i++) {
    float val = xin[tid + 256 * i];
    v[i] = val; s1 += val; s2 += val * val;
  }
  block_reduce_2(s1, s2);
  float mean = s1 * (1.f / 768.f);
  float var = s2 * (1.f / 768.f) - mean * mean;
  float inv = rsqrtf(var + 1e-6f);
#pragma unroll
  for (int i = 0; i < 3; i++) {
    int c = tid + 256 * i;
    out[c] = f2bf((v[i] - mean) * inv * g[c] + bta[c]);
  }
}

__global__ __launch_bounds__(256) void ln2_kernel(
    const float* __restrict__ x, const float* __restrict__ g,
    const float* __restrict__ bta, u16* __restrict__ yb) {
  int token = blockIdx.x;
  const float* xin = x + (size_t)token * 768;
  u16* out = yb + (size_t)token * 768;
  int tid = threadIdx.x;
  float v[3];
  float s1 = 0.f, s2 = 0.f;
#pragma unroll
  for (int i = 0; i < 3; i++) {
    float val = xin[tid + 256 * i];
    v[i] = val; s1 += val; s2 += val * val;
  }
  block_reduce_2(s1, s2);
  float mean = s1 * (1.f / 768.f);
  float var = s2 * (1.f / 768.f) - mean * mean;
  float inv = rsqrtf(var + 1e-6f);
#pragma unroll
  for (int i = 0; i < 3; i++) {
    int c = tid + 256 * i;
    out[c] = f2bf((v[i] - mean) * inv * g[c] + bta[c]);
  }
}

// Weight transpose -> bf16: w[K,N] -> o[N,K].
__global__ __launch_bounds__(256) void convT_kernel(
    const float* __restrict__ w, u16* __restrict__ o, int K, int N) {
  __shared__ float t[32][33];
  int n0 = blockIdx.x * 32, k0 = blockIdx.y * 32;
  int tid = threadIdx.x;
  {
    int i = tid >> 3, jq = (tid & 7) * 4;
    float4 v = *(const float4*)&w[(size_t)(k0 + i) * N + n0 + jq];
    t[i][jq] = v.x; t[i][jq + 1] = v.y; t[i][jq + 2] = v.z; t[i][jq + 3] = v.w;
  }
  __syncthreads();
  int j = tid >> 3, sub = tid & 7;
  u16 h[4];
#pragma unroll
  for (int m = 0; m < 4; m++) h[m] = f2bf(t[sub * 4 + m][j]);
  u32* dst = (u32*)(o + (size_t)(n0 + j) * K + (k0 + sub * 4));
  dst[0] = (u32)h[0] | ((u32)h[1] << 16);
  dst[1] = (u32)h[2] | ((u32)h[3] << 16);
}

// ---------------------------------------------------------------------------
// 128x128 MFMA GEMM, BK=64, 4 waves 2x2, 4x4 frags of 16x16x32_bf16.
// Linear LDS dest for global_load_lds; XOR swizzle q'=q^(row&7) on global
// source (store side) + ds_read (read side).
// EPI 0: bias + scatter qb/kb/vT (chunk-local)  1: bias + win reverse + resid
//        (rofs = global row offset for decode)  2: bias + GELU -> bf16
// EPI 3: bias + resid -> out (in-place RMW ok)
// ---------------------------------------------------------------------------
template <int EPI>
__global__ __launch_bounds__(256) void mgemm_kernel(
    const u16* __restrict__ A, const u16* __restrict__ BT,
    const float* __restrict__ bias, int M, int N, int Ke,
    float* __restrict__ outF, u16* __restrict__ outX,
    const float* __restrict__ resid, int rofs,
    u16* __restrict__ qb, u16* __restrict__ kb, u16* __restrict__ vT) {
  __shared__ u16 sA[128 * 64];
  __shared__ u16 sB[128 * 64];
  const int tid = threadIdx.x;
  const int wv = tid >> 6, lane = tid & 63;
  const int bm = blockIdx.y * 128, bn = blockIdx.x * 128;
  const int wr = wv >> 1, wc = wv & 1;

  size_t aOff[4], bOff[4];
  u16* ldsA[4];
  u16* ldsB[4];
#pragma unroll
  for (int i = 0; i < 4; i++) {
    int c = (wv * 4 + i) * 64 + lane;
    int row = c >> 3, qp = c & 7;
    int q = qp ^ (row & 7);
    int ar = bm + row;
    if (ar >= M) ar = M - 1;
    aOff[i] = (size_t)ar * Ke + q * 8;
    bOff[i] = (size_t)(bn + row) * Ke + q * 8;
    ldsA[i] = &sA[(wv * 4 + i) * 512];
    ldsB[i] = &sB[(wv * 4 + i) * 512];
  }

  f32x4 acc[4][4];
#pragma unroll
  for (int i = 0; i < 4; i++)
#pragma unroll
    for (int j = 0; j < 4; j++) acc[i][j] = (f32x4){0.f, 0.f, 0.f, 0.f};

  for (int k0 = 0; k0 < Ke; k0 += 64) {
    __syncthreads();
#pragma unroll
    for (int i = 0; i < 4; i++) gl_lds16(A + aOff[i] + k0, ldsA[i]);
#pragma unroll
    for (int i = 0; i < 4; i++) gl_lds16(BT + bOff[i] + k0, ldsB[i]);
    __syncthreads();

    short8 af[4][2], bf[4][2];
#pragma unroll
    for (int f = 0; f < 4; f++)
#pragma unroll
      for (int kh = 0; kh < 2; kh++) {
        int ra = wr * 64 + f * 16 + (lane & 15);
        int qa = kh * 4 + (lane >> 4);
        af[f][kh] = *(const short8*)&sA[ra * 64 + ((qa ^ (ra & 7)) * 8)];
        int rb = wc * 64 + f * 16 + (lane & 15);
        bf[f][kh] = *(const short8*)&sB[rb * 64 + ((qa ^ (rb & 7)) * 8)];
      }
#pragma unroll
    for (int kh = 0; kh < 2; kh++)
#pragma unroll
      for (int fi = 0; fi < 4; fi++)
#pragma unroll
        for (int fj = 0; fj < 4; fj++)
          acc[fi][fj] = __builtin_amdgcn_mfma_f32_16x16x32_bf16(
              af[fi][kh], bf[fj][kh], acc[fi][fj], 0, 0, 0);
  }

  // C/D layout: col = lane&15, row = (lane>>4)*4 + r
#pragma unroll
  for (int fi = 0; fi < 4; fi++) {
#pragma unroll
    for (int fj = 0; fj < 4; fj++) {
      int col = bn + wc * 64 + fj * 16 + (lane & 15);
      float bcol = bias[col];
#pragma unroll
      for (int r = 0; r < 4; r++) {
        int row = bm + wr * 64 + fi * 16 + (lane >> 4) * 4 + r;
        if (row >= M) continue;
        float v = acc[fi][fj][r] + bcol;
        if (EPI == 0) {
          int which = (col >= 1536) ? 2 : (col >= 768 ? 1 : 0);
          int cr = col - which * 768;
          int head = cr >> 6, d0 = cr & 63;
          int wl = row / 196, t = row - wl * 196;   // chunk-local
          int b2l = wl * 12 + head;
          if (which == 0)
            qb[((size_t)b2l * 196 + t) * 64 + d0] = f2bf(v);
          else if (which == 1)
            kb[((size_t)b2l * 196 + t) * 64 + d0] = f2bf(v);
          else
            vT[((size_t)b2l * 64 + d0) * 256 + t] = f2bf(v);
        } else if (EPI == 1) {
          int rg = row + rofs;                      // global window row
          int wi = rg / 196, t = rg - wi * 196;
          int b = wi / 25, rem = wi % 25;
          int hh = (rem / 5) * 14 + t / 14;
          int ww = (rem % 5) * 14 + t % 14;
          if (hh < 64 && ww < 64) {
            size_t off = ((size_t)((b * 64 + hh) * 64 + ww)) * 768 + col;
            outF[off] = resid[off] + v;
          }
        } else if (EPI == 2) {
          float gg = 0.5f * v * (1.f + erff(v * 0.70710678118654752f));
          outX[(size_t)row * N + col] = f2bf(gg);
        } else {
          size_t off = (size_t)row * N + col;
          outF[off] = v + resid[off];
        }
      }
    }
  }
}

// Rel-bias tables (chunk-local): relh[b2l,row,kh] = q . rel_pos_h[rh-kh+13].
__global__ __launch_bounds__(128) void rel_kernel(
    const u16* __restrict__ qb, const float* __restrict__ rph,
    const float* __restrict__ rpw, float* __restrict__ relh,
    float* __restrict__ relw) {
  int b2l = blockIdx.x / 196, row = blockIdx.x % 196;
  __shared__ float sq[64];
  int tid = threadIdx.x;
  if (tid < 64) sq[tid] = bf2f(qb[((size_t)b2l * 196 + row) * 64 + tid]);
  __syncthreads();
  int rh = row / 14, rw = row % 14;
  int t = tid & 63;
  if (t < 56) {
    int which = tid >> 6;  // 0: relh, 1: relw
    int kh = t >> 2, part = t & 3;
    int rel = (which ? rw : rh) - kh + 13;
    const float* R = (which ? rpw : rph) + (size_t)rel * 64 + part * 16;
    float p = 0.f;
#pragma unroll
    for (int d = 0; d < 16; d++) p += sq[part * 16 + d] * R[d];
    p += __shfl_down(p, 2, 4);
    p += __shfl_down(p, 1, 4);
    if (part == 0) {
      float* dst = which ? relw : relh;
      dst[((size_t)b2l * 196 + row) * 14 + kh] = p;
    }
  }
}

// ---------------------------------------------------------------------------
// 64x256-tile MFMA GEMM per b2l; 4 waves side-by-side, 4x4 frags each.
// Tile spans all 196 cols -> row softmax fuses in-block.
// EPI 0 (scores): S = qb@kb^T (Ke=64), *0.125 +rel, fused row softmax,
//   write pe bf16, zero k-pad cols [196,256).
// EPI 1 (pvT): outT = vT@pe^T (Ke=256), scatter bf16 into win_c (chunk-local).
// ---------------------------------------------------------------------------
template <int EPI>
__global__ __launch_bounds__(256) void sgemm64_kernel(
    const u16* __restrict__ Aall, const u16* __restrict__ BTall,
    int Ke, int Arows,
    const float* __restrict__ relh, const float* __restrict__ relw,
    u16* __restrict__ pe, u16* __restrict__ winx) {
  __shared__ u16 sA[64 * 64];
  __shared__ u16 sB[256 * 64];
  __shared__ float sred[64][4];
  const int tid = threadIdx.x;
  const int wv = tid >> 6, lane = tid & 63;
  const int b2l = blockIdx.y;
  const int bm = blockIdx.x * 64;
  const u16* A = Aall + (size_t)b2l * Arows * Ke;
  const u16* BT = BTall + (size_t)b2l * 196 * Ke;

  size_t aOff[2], bOff[8];
  u16* ldsA[2];
  u16* ldsB[8];
#pragma unroll
  for (int i = 0; i < 2; i++) {
    int c = (wv * 2 + i) * 64 + lane;
    int rl = c >> 3, qp = c & 7;
    int q = qp ^ (rl & 7);
    int ga = bm + rl;
    if (ga >= Arows) ga = Arows - 1;
    aOff[i] = (size_t)ga * Ke + q * 8;
    ldsA[i] = &sA[(wv * 2 + i) * 512];
  }
#pragma unroll
  for (int i = 0; i < 8; i++) {
    int c = (wv * 8 + i) * 64 + lane;
    int rl = c >> 3, qp = c & 7;
    int q = qp ^ (rl & 7);
    int gb = rl > 195 ? 195 : rl;
    bOff[i] = (size_t)gb * Ke + q * 8;
    ldsB[i] = &sB[(wv * 8 + i) * 512];
  }

  f32x4 acc[4][4];
#pragma unroll
  for (int i = 0; i < 4; i++)
#pragma unroll
    for (int j = 0; j < 4; j++) acc[i][j] = (f32x4){0.f, 0.f, 0.f, 0.f};

  for (int k0 = 0; k0 < Ke; k0 += 64) {
    __syncthreads();
#pragma unroll
    for (int i = 0; i < 2; i++) gl_lds16(A + aOff[i] + k0, ldsA[i]);
#pragma unroll
    for (int i = 0; i < 8; i++) gl_lds16(BT + bOff[i] + k0, ldsB[i]);
    __syncthreads();

    short8 af[4][2], bf[4][2];
#pragma unroll
    for (int f = 0; f < 4; f++)
#pragma unroll
      for (int kh = 0; kh < 2; kh++) {
        int ra = f * 16 + (lane & 15);
        int qa = kh * 4 + (lane >> 4);
        af[f][kh] = *(const short8*)&sA[ra * 64 + ((qa ^ (ra & 7)) * 8)];
        int rb = wv * 64 + f * 16 + (lane & 15);
        bf[f][kh] = *(const short8*)&sB[rb * 64 + ((qa ^ (rb & 7)) * 8)];
      }
#pragma unroll
    for (int kh = 0; kh < 2; kh++)
#pragma unroll
      for (int fi = 0; fi < 4; fi++)
#pragma unroll
        for (int fj = 0; fj < 4; fj++)
          acc[fi][fj] = __builtin_amdgcn_mfma_f32_16x16x32_bf16(
              af[fi][kh], bf[fj][kh], acc[fi][fj], 0, 0, 0);
  }

  if (EPI == 0) {
    // biased scores (invalid -> -3e38 finite sentinel)
#pragma unroll
    for (int fi = 0; fi < 4; fi++)
#pragma unroll
      for (int fj = 0; fj < 4; fj++)
#pragma unroll
        for (int r = 0; r < 4; r++) {
          int grow = bm + fi * 16 + (lane >> 4) * 4 + r;
          int col = wv * 64 + fj * 16 + (lane & 15);
          float v = -3.0e38f;
          if (grow < 196 && col < 196) {
            size_t rb = ((size_t)b2l * 196 + grow) * 14;
            v = acc[fi][fj][r] * 0.125f + relh[rb + col / 14] + relw[rb + col % 14];
          }
          acc[fi][fj][r] = v;
        }
    float red[4][4];
#pragma unroll
    for (int fi = 0; fi < 4; fi++)
#pragma unroll
      for (int r = 0; r < 4; r++) {
        float m = fmaxf(fmaxf(acc[fi][0][r], acc[fi][1][r]),
                        fmaxf(acc[fi][2][r], acc[fi][3][r]));
#pragma unroll
        for (int msk = 1; msk < 16; msk <<= 1) m = fmaxf(m, __shfl_xor(m, msk, 64));
        red[fi][r] = m;
      }
    if ((lane & 15) == 0)
#pragma unroll
      for (int fi = 0; fi < 4; fi++)
#pragma unroll
        for (int r = 0; r < 4; r++)
          sred[fi * 16 + (lane >> 4) * 4 + r][wv] = red[fi][r];
    __syncthreads();
#pragma unroll
    for (int fi = 0; fi < 4; fi++)
#pragma unroll
      for (int r = 0; r < 4; r++) {
        int rl = fi * 16 + (lane >> 4) * 4 + r;
        red[fi][r] = fmaxf(fmaxf(sred[rl][0], sred[rl][1]),
                           fmaxf(sred[rl][2], sred[rl][3]));
      }
    __syncthreads();  // WAR before sum phase reuses sred
#pragma unroll
    for (int fi = 0; fi < 4; fi++)
#pragma unroll
      for (int fj = 0; fj < 4; fj++)
#pragma unroll
        for (int r = 0; r < 4; r++)
          acc[fi][fj][r] = __expf(acc[fi][fj][r] - red[fi][r]);
#pragma unroll
    for (int fi = 0; fi < 4; fi++)
#pragma unroll
      for (int r = 0; r < 4; r++) {
        float s = acc[fi][0][r] + acc[fi][1][r] + acc[fi][2][r] + acc[fi][3][r];
#pragma unroll
        for (int msk = 1; msk < 16; msk <<= 1) s += __shfl_xor(s, msk, 64);
        red[fi][r] = s;
      }
    if ((lane & 15) == 0)
#pragma unroll
      for (int fi = 0; fi < 4; fi++)
#pragma unroll
        for (int r = 0; r < 4; r++)
          sred[fi * 16 + (lane >> 4) * 4 + r][wv] = red[fi][r];
    __syncthreads();
#pragma unroll
    for (int fi = 0; fi < 4; fi++)
#pragma unroll
      for (int r = 0; r < 4; r++) {
        int rl = fi * 16 + (lane >> 4) * 4 + r;
        red[fi][r] = 1.f / (sred[rl][0] + sred[rl][1] + sred[rl][2] + sred[rl][3]);
      }
#pragma unroll
    for (int fi = 0; fi < 4; fi++)
#pragma unroll
      for (int fj = 0; fj < 4; fj++)
#pragma unroll
        for (int r = 0; r < 4; r++) {
          int grow = bm + fi * 16 + (lane >> 4) * 4 + r;
          int col = wv * 64 + fj * 16 + (lane & 15);
          if (grow < 196 && col < 196)
            pe[((size_t)b2l * 196 + grow) * 256 + col] =
                f2bf(acc[fi][fj][r] * red[fi][r]);
        }
    // zero k-pad cols [196,256) for this tile's valid rows
    int nrow = 196 - bm; if (nrow > 64) nrow = 64;
    for (int z = tid; z < nrow * 30; z += 256) {
      int r = z / 30, idx = z % 30;
      *(u32*)&pe[((size_t)b2l * 196 + bm + r) * 256 + 196 + idx * 2] = 0;
    }
  } else {
    // pvT: row=d (bm=0), col=t; scatter bf16 into win_c (chunk-local)
    int wi_l = b2l / 12, head = b2l - wi_l * 12;
#pragma unroll
    for (int fi = 0; fi < 4; fi++)
#pragma unroll
      for (int fj = 0; fj < 4; fj++)
#pragma unroll
        for (int r = 0; r < 4; r++) {
          int d = fi * 16 + (lane >> 4) * 4 + r;
          int t = wv * 64 + fj * 16 + (lane & 15);
          if (t < 196)
            winx[((size_t)wi_l * 196 + t) * 768 + head * 64 + d] =
                f2bf(acc[fi][fj][r]);
        }
  }
}

extern "C" void kernel_launch(void* const* d_in, const int* in_sizes, int n_in,
                              void* d_out, int out_size, void* d_ws, size_t ws_size,
                              hipStream_t stream) {
  const float* x = (const float*)d_in[0];
  const float* ln1_g = (const float*)d_in[1];
  const float* ln1_b = (const float*)d_in[2];
  const float* w_qkv = (const float*)d_in[3];
  const float* b_qkv = (const float*)d_in[4];
  const float* w_proj = (const float*)d_in[5];
  const float* b_proj = (const float*)d_in[6];
  const float* rph = (const float*)d_in[7];
  const float* rpw = (const float*)d_in[8];
  const float* ln2_g = (const float*)d_in[9];
  const float* ln2_b = (const float*)d_in[10];
  const float* w_fc1 = (const float*)d_in[11];
  const float* b_fc1 = (const float*)d_in[12];
  const float* w_fc2 = (const float*)d_in[13];
  const float* b_fc2 = (const float*)d_in[14];
  float* out = (float*)d_out;
  char* wsb = (char*)d_ws;

  // --- adaptive tiering on ws_size (constant per session -> graph-safe) ---
  const size_t WB = 14155776ull;       // weights pool
  const size_t PERW = 2764032ull;      // attn bytes per window
  static const int nwCand[9] = {100, 50, 25, 20, 10, 5, 4, 2, 1};
  int NW = 0;
  for (int i = 0; i < 9; i++)
    if (WB + (size_t)nwCand[i] * PERW <= ws_size) { NW = nwCand[i]; break; }
  int R = 0;
  for (int rc = 16384; rc >= 128; rc >>= 1)
    if (WB + (size_t)rc * 7680ull <= ws_size) { R = rc; break; }
  if (NW == 0 || R == 0) return;  // diagnostic guard (min need ~17MB)

  u16* wqkvT = (u16*)(wsb);                       // [2304,768]  3,538,944
  u16* wprojT = (u16*)(wsb + 3538944);            // [768,768]   1,179,648
  u16* wfc1T = (u16*)(wsb + 4718592);             // [3072,768]  4,718,592
  u16* wfc2T = (u16*)(wsb + 9437184);             // [768,3072]  4,718,592
  char* pool = wsb + WB;
  u16* win_c = (u16*)pool;                        // [NW*196,768]
  u16* qb_c = (u16*)(pool + (size_t)NW * 301056);
  u16* kb_c = (u16*)(pool + (size_t)NW * 602112);
  u16* vT_c = (u16*)(pool + (size_t)NW * 903168);
  float* relh_c = (float*)(pool + (size_t)NW * 1296384);
  float* relw_c = (float*)(pool + (size_t)NW * 1428096);
  u16* pe_c = (u16*)(pool + (size_t)NW * 1559808);  // ends NW*2764032
  u16* y_c = (u16*)pool;                          // MLP overlay [R,768]
  u16* h_c = (u16*)(pool + (size_t)R * 1536);     // [R,3072]

  convT_kernel<<<dim3(72, 24), 256, 0, stream>>>(w_qkv, wqkvT, 768, 2304);
  convT_kernel<<<dim3(24, 24), 256, 0, stream>>>(w_proj, wprojT, 768, 768);
  convT_kernel<<<dim3(96, 24), 256, 0, stream>>>(w_fc1, wfc1T, 768, 3072);
  convT_kernel<<<dim3(24, 96), 256, 0, stream>>>(w_fc2, wfc2T, 3072, 768);

  const int MW = NW * 196;               // rows per window chunk
  const int gy = (MW + 127) / 128;
  const int nchunks = 100 / NW;
  for (int c = 0; c < nchunks; c++) {
    ln1_win_kernel<<<MW, 256, 0, stream>>>(x, ln1_g, ln1_b, win_c, c * MW);
    mgemm_kernel<0><<<dim3(18, gy), 256, 0, stream>>>(
        win_c, wqkvT, b_qkv, MW, 2304, 768, nullptr, nullptr, nullptr, 0,
        qb_c, kb_c, vT_c);
    rel_kernel<<<NW * 12 * 196, 128, 0, stream>>>(qb_c, rph, rpw, relh_c, relw_c);
    sgemm64_kernel<0><<<dim3(4, NW * 12), 256, 0, stream>>>(
        qb_c, kb_c, 64, 196, relh_c, relw_c, pe_c, nullptr);
    sgemm64_kernel<1><<<dim3(1, NW * 12), 256, 0, stream>>>(
        vT_c, pe_c, 256, 64, nullptr, nullptr, nullptr, win_c);
    mgemm_kernel<1><<<dim3(6, gy), 256, 0, stream>>>(
        win_c, wprojT, b_proj, MW, 768, 768, out, nullptr, x, c * MW,
        nullptr, nullptr, nullptr);  // x1 lives in d_out
  }
  for (int r0 = 0; r0 < 16384; r0 += R) {
    ln2_kernel<<<R, 256, 0, stream>>>(out + (size_t)r0 * 768, ln2_g, ln2_b, y_c);
    mgemm_kernel<2><<<dim3(24, R / 128), 256, 0, stream>>>(
        y_c, wfc1T, b_fc1, R, 3072, 768, nullptr, h_c, nullptr, 0,
        nullptr, nullptr, nullptr);
    mgemm_kernel<3><<<dim3(6, R / 128), 256, 0, stream>>>(
        h_c, wfc2T, b_fc2, R, 768, 3072, out + (size_t)r0 * 768, nullptr,
        out + (size_t)r0 * 768, 0, nullptr, nullptr, nullptr);
  }
}

// Round 7
// 916.068 us; speedup vs baseline: 1.1186x; 1.1186x over previous
//
#include <hip/hip_runtime.h>
#include <hip/hip_bf16.h>
#include <math.h>

// ---------------------------------------------------------------------------
// SwinTransformerBlock — plain-bf16 MFMA pipeline, ws_size-ADAPTIVE chunking.
//   B=4 H=W=64 C=768, WS=14, NH=12, HD=64. Hp=Wp=70, 100 windows, T=196.
// R7 changes vs R6 (passing, 1024us): tanh-GELU (erff was ~40% of fc1 VALU),
// per-b2 rel kernel with LDS tables, LDS-staged rel in sgemm<0> epilogue,
// packed u64 stores for vT / pvT scatters. Everything else identical.
// ---------------------------------------------------------------------------

typedef unsigned short u16;
typedef unsigned int u32;
typedef unsigned long long u64;
typedef __attribute__((ext_vector_type(8))) short short8;
typedef __attribute__((ext_vector_type(4))) float f32x4;

__device__ __forceinline__ u16 f2bf(float x) {  // RNE f32->bf16
  u32 u = __float_as_uint(x);
  u32 r = (u + 0x7fffu + ((u >> 16) & 1u)) >> 16;
  return (u16)r;
}
__device__ __forceinline__ float bf2f(u16 h) { return __uint_as_float(((u32)h) << 16); }

__device__ __forceinline__ void gl_lds16(const void* g, void* l) {
  __builtin_amdgcn_global_load_lds((const __attribute__((address_space(1))) void*)g,
                                   (__attribute__((address_space(3))) void*)l, 16, 0, 0);
}

__device__ __forceinline__ void block_reduce_2(float& s1, float& s2) {
#pragma unroll
  for (int off = 32; off > 0; off >>= 1) {
    s1 += __shfl_down(s1, off, 64);
    s2 += __shfl_down(s2, off, 64);
  }
  __shared__ float sb[4][2];
  int lane = threadIdx.x & 63;
  int wv = threadIdx.x >> 6;
  if (lane == 0) { sb[wv][0] = s1; sb[wv][1] = s2; }
  __syncthreads();
  s1 = sb[0][0] + sb[1][0] + sb[2][0] + sb[3][0];
  s2 = sb[0][1] + sb[1][1] + sb[2][1] + sb[3][1];
}

// LN1 + window partition (chunk-local out, global decode via tofs).
__global__ __launch_bounds__(256) void ln1_win_kernel(
    const float* __restrict__ x, const float* __restrict__ g,
    const float* __restrict__ bta, u16* __restrict__ wb, int tofs) {
  int token_g = tofs + blockIdx.x;
  int wi = token_g / 196, t = token_g % 196;
  int b = wi / 25, rem = wi % 25;
  int h = (rem / 5) * 14 + t / 14, w = (rem % 5) * 14 + t % 14;
  u16* out = wb + (size_t)blockIdx.x * 768;
  int tid = threadIdx.x;
  if (h >= 64 || w >= 64) {  // zero pad (pad applied AFTER LN in reference)
#pragma unroll
    for (int i = 0; i < 3; i++) out[tid + 256 * i] = 0;
    return;
  }
  const float* xin = x + ((size_t)((b * 64 + h) * 64 + w)) * 768;
  float v[3];
  float s1 = 0.f, s2 = 0.f;
#pragma unroll
  for (int i = 0; i < 3; i++) {
    float val = xin[tid + 256 * i];
    v[i] = val; s1 += val; s2 += val * val;
  }
  block_reduce_2(s1, s2);
  float mean = s1 * (1.f / 768.f);
  float var = s2 * (1.f / 768.f) - mean * mean;
  float inv = rsqrtf(var + 1e-6f);
#pragma unroll
  for (int i = 0; i < 3; i++) {
    int c = tid + 256 * i;
    out[c] = f2bf((v[i] - mean) * inv * g[c] + bta[c]);
  }
}

__global__ __launch_bounds__(256) void ln2_kernel(
    const float* __restrict__ x, const float* __restrict__ g,
    const float* __restrict__ bta, u16* __restrict__ yb) {
  int token = blockIdx.x;
  const float* xin = x + (size_t)token * 768;
  u16* out = yb + (size_t)token * 768;
  int tid = threadIdx.x;
  float v[3];
  float s1 = 0.f, s2 = 0.f;
#pragma unroll
  for (int i = 0; i < 3; i++) {
    float val = xin[tid + 256 * i];
    v[i] = val; s1 += val; s2 += val * val;
  }
  block_reduce_2(s1, s2);
  float mean = s1 * (1.f / 768.f);
  float var = s2 * (1.f / 768.f) - mean * mean;
  float inv = rsqrtf(var + 1e-6f);
#pragma unroll
  for (int i = 0; i < 3; i++) {
    int c = tid + 256 * i;
    out[c] = f2bf((v[i] - mean) * inv * g[c] + bta[c]);
  }
}

// Weight transpose -> bf16: w[K,N] -> o[N,K].
__global__ __launch_bounds__(256) void convT_kernel(
    const float* __restrict__ w, u16* __restrict__ o, int K, int N) {
  __shared__ float t[32][33];
  int n0 = blockIdx.x * 32, k0 = blockIdx.y * 32;
  int tid = threadIdx.x;
  {
    int i = tid >> 3, jq = (tid & 7) * 4;
    float4 v = *(const float4*)&w[(size_t)(k0 + i) * N + n0 + jq];
    t[i][jq] = v.x; t[i][jq + 1] = v.y; t[i][jq + 2] = v.z; t[i][jq + 3] = v.w;
  }
  __syncthreads();
  int j = tid >> 3, sub = tid & 7;
  u16 h[4];
#pragma unroll
  for (int m = 0; m < 4; m++) h[m] = f2bf(t[sub * 4 + m][j]);
  u32* dst = (u32*)(o + (size_t)(n0 + j) * K + (k0 + sub * 4));
  dst[0] = (u32)h[0] | ((u32)h[1] << 16);
  dst[1] = (u32)h[2] | ((u32)h[3] << 16);
}

// ---------------------------------------------------------------------------
// 128x128 MFMA GEMM, BK=64, 4 waves 2x2, 4x4 frags of 16x16x32_bf16.
// EPI 0: bias + scatter qb/kb/vT (vT packed u64)  1: bias + win rev + resid
// EPI 2: bias + tanh-GELU -> bf16                 3: bias + resid -> out
// ---------------------------------------------------------------------------
template <int EPI>
__global__ __launch_bounds__(256) void mgemm_kernel(
    const u16* __restrict__ A, const u16* __restrict__ BT,
    const float* __restrict__ bias, int M, int N, int Ke,
    float* __restrict__ outF, u16* __restrict__ outX,
    const float* __restrict__ resid, int rofs,
    u16* __restrict__ qb, u16* __restrict__ kb, u16* __restrict__ vT) {
  __shared__ u16 sA[128 * 64];
  __shared__ u16 sB[128 * 64];
  const int tid = threadIdx.x;
  const int wv = tid >> 6, lane = tid & 63;
  const int bm = blockIdx.y * 128, bn = blockIdx.x * 128;
  const int wr = wv >> 1, wc = wv & 1;

  size_t aOff[4], bOff[4];
  u16* ldsA[4];
  u16* ldsB[4];
#pragma unroll
  for (int i = 0; i < 4; i++) {
    int c = (wv * 4 + i) * 64 + lane;
    int row = c >> 3, qp = c & 7;
    int q = qp ^ (row & 7);
    int ar = bm + row;
    if (ar >= M) ar = M - 1;
    aOff[i] = (size_t)ar * Ke + q * 8;
    bOff[i] = (size_t)(bn + row) * Ke + q * 8;
    ldsA[i] = &sA[(wv * 4 + i) * 512];
    ldsB[i] = &sB[(wv * 4 + i) * 512];
  }

  f32x4 acc[4][4];
#pragma unroll
  for (int i = 0; i < 4; i++)
#pragma unroll
    for (int j = 0; j < 4; j++) acc[i][j] = (f32x4){0.f, 0.f, 0.f, 0.f};

  for (int k0 = 0; k0 < Ke; k0 += 64) {
    __syncthreads();
#pragma unroll
    for (int i = 0; i < 4; i++) gl_lds16(A + aOff[i] + k0, ldsA[i]);
#pragma unroll
    for (int i = 0; i < 4; i++) gl_lds16(BT + bOff[i] + k0, ldsB[i]);
    __syncthreads();

    short8 af[4][2], bf[4][2];
#pragma unroll
    for (int f = 0; f < 4; f++)
#pragma unroll
      for (int kh = 0; kh < 2; kh++) {
        int ra = wr * 64 + f * 16 + (lane & 15);
        int qa = kh * 4 + (lane >> 4);
        af[f][kh] = *(const short8*)&sA[ra * 64 + ((qa ^ (ra & 7)) * 8)];
        int rb = wc * 64 + f * 16 + (lane & 15);
        bf[f][kh] = *(const short8*)&sB[rb * 64 + ((qa ^ (rb & 7)) * 8)];
      }
#pragma unroll
    for (int kh = 0; kh < 2; kh++)
#pragma unroll
      for (int fi = 0; fi < 4; fi++)
#pragma unroll
        for (int fj = 0; fj < 4; fj++)
          acc[fi][fj] = __builtin_amdgcn_mfma_f32_16x16x32_bf16(
              af[fi][kh], bf[fj][kh], acc[fi][fj], 0, 0, 0);
  }

  // C/D layout: col = lane&15, row = (lane>>4)*4 + r
#pragma unroll
  for (int fi = 0; fi < 4; fi++) {
#pragma unroll
    for (int fj = 0; fj < 4; fj++) {
      int col = bn + wc * 64 + fj * 16 + (lane & 15);
      float bcol = bias[col];
      int row0 = bm + wr * 64 + fi * 16 + (lane >> 4) * 4;
      if (EPI == 0 && col >= 1536) {
        // vT packed path: 4 consecutive t (row0%4==0, 196%4==0 -> never
        // crosses a window boundary), 8B-aligned u64 store.
        if (row0 < M) {
          int cr = col - 1536;
          int head = cr >> 6, d0 = cr & 63;
          int wl = row0 / 196, t0 = row0 - wl * 196;
          int b2l = wl * 12 + head;
          u64 pack = 0;
#pragma unroll
          for (int r = 0; r < 4; r++)
            pack |= (u64)f2bf(acc[fi][fj][r] + bcol) << (16 * r);
          *(u64*)&vT[((size_t)b2l * 64 + d0) * 256 + t0] = pack;
        }
        continue;
      }
#pragma unroll
      for (int r = 0; r < 4; r++) {
        int row = row0 + r;
        if (row >= M) continue;
        float v = acc[fi][fj][r] + bcol;
        if (EPI == 0) {
          int which = (col >= 768) ? 1 : 0;
          int cr = col - which * 768;
          int head = cr >> 6, d0 = cr & 63;
          int wl = row / 196, t = row - wl * 196;   // chunk-local
          int b2l = wl * 12 + head;
          if (which == 0)
            qb[((size_t)b2l * 196 + t) * 64 + d0] = f2bf(v);
          else
            kb[((size_t)b2l * 196 + t) * 64 + d0] = f2bf(v);
        } else if (EPI == 1) {
          int rg = row + rofs;                      // global window row
          int wi = rg / 196, t = rg - wi * 196;
          int b = wi / 25, rem = wi % 25;
          int hh = (rem / 5) * 14 + t / 14;
          int ww = (rem % 5) * 14 + t % 14;
          if (hh < 64 && ww < 64) {
            size_t off = ((size_t)((b * 64 + hh) * 64 + ww)) * 768 + col;
            outF[off] = resid[off] + v;
          }
        } else if (EPI == 2) {
          // tanh-GELU (err ~1e-3 vs exact erf; threshold is bf16-level)
          float y = 0.79788456f * (v + 0.044715f * v * v * v);
          float ay = fabsf(y);
          float e = __expf(-2.f * ay);
          float th = (1.f - e) / (1.f + e);
          th = (y < 0.f) ? -th : th;
          outX[(size_t)row * N + col] = f2bf(0.5f * v * (1.f + th));
        } else {
          size_t off = (size_t)row * N + col;
          outF[off] = v + resid[off];
        }
      }
    }
  }
}

// Rel-bias tables, one block per b2l: relh[b2l,row,kh] = q . rph[rh-kh+13].
// q (bf16, padded stride 68) + both 27x64 tables (f32, padded stride 66) in LDS.
__global__ __launch_bounds__(256) void rel_kernel(
    const u16* __restrict__ qb, const float* __restrict__ rph,
    const float* __restrict__ rpw, float* __restrict__ relh,
    float* __restrict__ relw) {
  __shared__ u16 sq[196 * 68];
  __shared__ float sRt[2][27 * 66];
  int b2l = blockIdx.x;
  int tid = threadIdx.x;
  const u32* qsrc = (const u32*)(qb + (size_t)b2l * 12544);
  for (int i = tid; i < 6272; i += 256) {      // 196 rows x 32 u32
    int row = i >> 5, p = i & 31;
    *(u32*)&sq[row * 68 + p * 2] = qsrc[i];
  }
  for (int i = tid; i < 1728; i += 256) {      // 27 x 64 each
    int r = i >> 6, c = i & 63;
    sRt[0][r * 66 + c] = rph[i];
    sRt[1][r * 66 + c] = rpw[i];
  }
  __syncthreads();
  for (int o = tid; o < 5488; o += 256) {      // 2 x 196 x 14 outputs
    int which = o >= 2744;
    int oo = o - which * 2744;
    int row = oo / 14, kh = oo - row * 14;
    int rr = which ? (row % 14) : (row / 14);
    int idx = rr - kh + 13;
    const float* tab = &sRt[which][idx * 66];
    const u16* qrow = &sq[row * 68];
    float p = 0.f;
#pragma unroll
    for (int d = 0; d < 64; d += 2) {
      u32 qp = *(const u32*)&qrow[d];
      p += __uint_as_float(qp << 16) * tab[d];
      p += __uint_as_float(qp & 0xffff0000u) * tab[d + 1];
    }
    (which ? relw : relh)[((size_t)b2l * 196 + row) * 14 + kh] = p;
  }
}

// ---------------------------------------------------------------------------
// 64x256-tile MFMA GEMM per b2l; 4 waves side-by-side, 4x4 frags each.
// EPI 0 (scores): S = qb@kb^T (Ke=64), *0.125 + rel (LDS-staged), fused row
//   softmax, write pe bf16, zero k-pad cols [196,256).
// EPI 1 (pvT): outT = vT@pe^T (Ke=256), packed u64 scatter into win_c.
// ---------------------------------------------------------------------------
template <int EPI>
__global__ __launch_bounds__(256) void sgemm64_kernel(
    const u16* __restrict__ Aall, const u16* __restrict__ BTall,
    int Ke, int Arows,
    const float* __restrict__ relh, const float* __restrict__ relw,
    u16* __restrict__ pe, u16* __restrict__ winx) {
  __shared__ u16 sA[64 * 64];
  __shared__ u16 sB[256 * 64];
  __shared__ float sred[64][4];
  const int tid = threadIdx.x;
  const int wv = tid >> 6, lane = tid & 63;
  const int b2l = blockIdx.y;
  const int bm = blockIdx.x * 64;
  const u16* A = Aall + (size_t)b2l * Arows * Ke;
  const u16* BT = BTall + (size_t)b2l * 196 * Ke;

  size_t aOff[2], bOff[8];
  u16* ldsA[2];
  u16* ldsB[8];
#pragma unroll
  for (int i = 0; i < 2; i++) {
    int c = (wv * 2 + i) * 64 + lane;
    int rl = c >> 3, qp = c & 7;
    int q = qp ^ (rl & 7);
    int ga = bm + rl;
    if (ga >= Arows) ga = Arows - 1;
    aOff[i] = (size_t)ga * Ke + q * 8;
    ldsA[i] = &sA[(wv * 2 + i) * 512];
  }
#pragma unroll
  for (int i = 0; i < 8; i++) {
    int c = (wv * 8 + i) * 64 + lane;
    int rl = c >> 3, qp = c & 7;
    int q = qp ^ (rl & 7);
    int gb = rl > 195 ? 195 : rl;
    bOff[i] = (size_t)gb * Ke + q * 8;
    ldsB[i] = &sB[(wv * 8 + i) * 512];
  }

  f32x4 acc[4][4];
#pragma unroll
  for (int i = 0; i < 4; i++)
#pragma unroll
    for (int j = 0; j < 4; j++) acc[i][j] = (f32x4){0.f, 0.f, 0.f, 0.f};

  for (int k0 = 0; k0 < Ke; k0 += 64) {
    __syncthreads();
#pragma unroll
    for (int i = 0; i < 2; i++) gl_lds16(A + aOff[i] + k0, ldsA[i]);
#pragma unroll
    for (int i = 0; i < 8; i++) gl_lds16(BT + bOff[i] + k0, ldsB[i]);
    __syncthreads();

    short8 af[4][2], bf[4][2];
#pragma unroll
    for (int f = 0; f < 4; f++)
#pragma unroll
      for (int kh = 0; kh < 2; kh++) {
        int ra = f * 16 + (lane & 15);
        int qa = kh * 4 + (lane >> 4);
        af[f][kh] = *(const short8*)&sA[ra * 64 + ((qa ^ (ra & 7)) * 8)];
        int rb = wv * 64 + f * 16 + (lane & 15);
        bf[f][kh] = *(const short8*)&sB[rb * 64 + ((qa ^ (rb & 7)) * 8)];
      }
#pragma unroll
    for (int kh = 0; kh < 2; kh++)
#pragma unroll
      for (int fi = 0; fi < 4; fi++)
#pragma unroll
        for (int fj = 0; fj < 4; fj++)
          acc[fi][fj] = __builtin_amdgcn_mfma_f32_16x16x32_bf16(
              af[fi][kh], bf[fj][kh], acc[fi][fj], 0, 0, 0);
  }

  if (EPI == 0) {
    // Stage this block's rel slices into LDS (reuse sA: 64*14*2 f32 = 7KB).
    __syncthreads();  // all waves done reading sA/sB fragments
    float* sRel = (float*)sA;
    {
      size_t base = ((size_t)b2l * 196 + bm) * 14;  // contiguous 896 floats
      int nval = (196 - bm < 64 ? 196 - bm : 64) * 14;
      for (int i = tid; i < 896; i += 256) {
        sRel[i] = (i < nval) ? relh[base + i] : 0.f;
        sRel[896 + i] = (i < nval) ? relw[base + i] : 0.f;
      }
    }
    __syncthreads();
    // biased scores (invalid -> -3e38 finite sentinel)
#pragma unroll
    for (int fi = 0; fi < 4; fi++)
#pragma unroll
      for (int fj = 0; fj < 4; fj++)
#pragma unroll
        for (int r = 0; r < 4; r++) {
          int grow = bm + fi * 16 + (lane >> 4) * 4 + r;
          int col = wv * 64 + fj * 16 + (lane & 15);
          float v = -3.0e38f;
          if (grow < 196 && col < 196) {
            int lr = grow - bm;
            v = acc[fi][fj][r] * 0.125f + sRel[lr * 14 + col / 14] +
                sRel[896 + lr * 14 + col % 14];
          }
          acc[fi][fj][r] = v;
        }
    float red[4][4];
#pragma unroll
    for (int fi = 0; fi < 4; fi++)
#pragma unroll
      for (int r = 0; r < 4; r++) {
        float m = fmaxf(fmaxf(acc[fi][0][r], acc[fi][1][r]),
                        fmaxf(acc[fi][2][r], acc[fi][3][r]));
#pragma unroll
        for (int msk = 1; msk < 16; msk <<= 1) m = fmaxf(m, __shfl_xor(m, msk, 64));
        red[fi][r] = m;
      }
    if ((lane & 15) == 0)
#pragma unroll
      for (int fi = 0; fi < 4; fi++)
#pragma unroll
        for (int r = 0; r < 4; r++)
          sred[fi * 16 + (lane >> 4) * 4 + r][wv] = red[fi][r];
    __syncthreads();
#pragma unroll
    for (int fi = 0; fi < 4; fi++)
#pragma unroll
      for (int r = 0; r < 4; r++) {
        int rl = fi * 16 + (lane >> 4) * 4 + r;
        red[fi][r] = fmaxf(fmaxf(sred[rl][0], sred[rl][1]),
                           fmaxf(sred[rl][2], sred[rl][3]));
      }
    __syncthreads();  // WAR before sum phase reuses sred
#pragma unroll
    for (int fi = 0; fi < 4; fi++)
#pragma unroll
      for (int fj = 0; fj < 4; fj++)
#pragma unroll
        for (int r = 0; r < 4; r++)
          acc[fi][fj][r] = __expf(acc[fi][fj][r] - red[fi][r]);
#pragma unroll
    for (int fi = 0; fi < 4; fi++)
#pragma unroll
      for (int r = 0; r < 4; r++) {
        float s = acc[fi][0][r] + acc[fi][1][r] + acc[fi][2][r] + acc[fi][3][r];
#pragma unroll
        for (int msk = 1; msk < 16; msk <<= 1) s += __shfl_xor(s, msk, 64);
        red[fi][r] = s;
      }
    if ((lane & 15) == 0)
#pragma unroll
      for (int fi = 0; fi < 4; fi++)
#pragma unroll
        for (int r = 0; r < 4; r++)
          sred[fi * 16 + (lane >> 4) * 4 + r][wv] = red[fi][r];
    __syncthreads();
#pragma unroll
    for (int fi = 0; fi < 4; fi++)
#pragma unroll
      for (int r = 0; r < 4; r++) {
        int rl = fi * 16 + (lane >> 4) * 4 + r;
        red[fi][r] = 1.f / (sred[rl][0] + sred[rl][1] + sred[rl][2] + sred[rl][3]);
      }
#pragma unroll
    for (int fi = 0; fi < 4; fi++)
#pragma unroll
      for (int fj = 0; fj < 4; fj++)
#pragma unroll
        for (int r = 0; r < 4; r++) {
          int grow = bm + fi * 16 + (lane >> 4) * 4 + r;
          int col = wv * 64 + fj * 16 + (lane & 15);
          if (grow < 196 && col < 196)
            pe[((size_t)b2l * 196 + grow) * 256 + col] =
                f2bf(acc[fi][fj][r] * red[fi][r]);
        }
    // zero k-pad cols [196,256) for this tile's valid rows
    int nrow = 196 - bm; if (nrow > 64) nrow = 64;
    for (int z = tid; z < nrow * 30; z += 256) {
      int r = z / 30, idx = z % 30;
      *(u32*)&pe[((size_t)b2l * 196 + bm + r) * 256 + 196 + idx * 2] = 0;
    }
  } else {
    // pvT: row=d (bm=0), col=t; packed u64 scatter (4 consecutive d).
    int wi_l = b2l / 12, head = b2l - wi_l * 12;
#pragma unroll
    for (int fi = 0; fi < 4; fi++) {
      int d0 = fi * 16 + (lane >> 4) * 4;
#pragma unroll
      for (int fj = 0; fj < 4; fj++) {
        int t = wv * 64 + fj * 16 + (lane & 15);
        if (t < 196) {
          u64 pack = 0;
#pragma unroll
          for (int r = 0; r < 4; r++)
            pack |= (u64)f2bf(acc[fi][fj][r]) << (16 * r);
          *(u64*)&winx[((size_t)wi_l * 196 + t) * 768 + head * 64 + d0] = pack;
        }
      }
    }
  }
}

extern "C" void kernel_launch(void* const* d_in, const int* in_sizes, int n_in,
                              void* d_out, int out_size, void* d_ws, size_t ws_size,
                              hipStream_t stream) {
  const float* x = (const float*)d_in[0];
  const float* ln1_g = (const float*)d_in[1];
  const float* ln1_b = (const float*)d_in[2];
  const float* w_qkv = (const float*)d_in[3];
  const float* b_qkv = (const float*)d_in[4];
  const float* w_proj = (const float*)d_in[5];
  const float* b_proj = (const float*)d_in[6];
  const float* rph = (const float*)d_in[7];
  const float* rpw = (const float*)d_in[8];
  const float* ln2_g = (const float*)d_in[9];
  const float* ln2_b = (const float*)d_in[10];
  const float* w_fc1 = (const float*)d_in[11];
  const float* b_fc1 = (const float*)d_in[12];
  const float* w_fc2 = (const float*)d_in[13];
  const float* b_fc2 = (const float*)d_in[14];
  float* out = (float*)d_out;
  char* wsb = (char*)d_ws;

  // --- adaptive tiering on ws_size (constant per session -> graph-safe) ---
  const size_t WB = 14155776ull;       // weights pool
  const size_t PERW = 2764032ull;      // attn bytes per window
  static const int nwCand[9] = {100, 50, 25, 20, 10, 5, 4, 2, 1};
  int NW = 0;
  for (int i = 0; i < 9; i++)
    if (WB + (size_t)nwCand[i] * PERW <= ws_size) { NW = nwCand[i]; break; }
  int R = 0;
  for (int rc = 16384; rc >= 128; rc >>= 1)
    if (WB + (size_t)rc * 7680ull <= ws_size) { R = rc; break; }
  if (NW == 0 || R == 0) return;  // diagnostic guard (min need ~17MB)

  u16* wqkvT = (u16*)(wsb);                       // [2304,768]  3,538,944
  u16* wprojT = (u16*)(wsb + 3538944);            // [768,768]   1,179,648
  u16* wfc1T = (u16*)(wsb + 4718592);             // [3072,768]  4,718,592
  u16* wfc2T = (u16*)(wsb + 9437184);             // [768,3072]  4,718,592
  char* pool = wsb + WB;
  u16* win_c = (u16*)pool;                        // [NW*196,768]
  u16* qb_c = (u16*)(pool + (size_t)NW * 301056);
  u16* kb_c = (u16*)(pool + (size_t)NW * 602112);
  u16* vT_c = (u16*)(pool + (size_t)NW * 903168);
  float* relh_c = (float*)(pool + (size_t)NW * 1296384);
  float* relw_c = (float*)(pool + (size_t)NW * 1428096);
  u16* pe_c = (u16*)(pool + (size_t)NW * 1559808);  // ends NW*2764032
  u16* y_c = (u16*)pool;                          // MLP overlay [R,768]
  u16* h_c = (u16*)(pool + (size_t)R * 1536);     // [R,3072]

  convT_kernel<<<dim3(72, 24), 256, 0, stream>>>(w_qkv, wqkvT, 768, 2304);
  convT_kernel<<<dim3(24, 24), 256, 0, stream>>>(w_proj, wprojT, 768, 768);
  convT_kernel<<<dim3(96, 24), 256, 0, stream>>>(w_fc1, wfc1T, 768, 3072);
  convT_kernel<<<dim3(24, 96), 256, 0, stream>>>(w_fc2, wfc2T, 3072, 768);

  const int MW = NW * 196;               // rows per window chunk
  const int gy = (MW + 127) / 128;
  const int nchunks = 100 / NW;
  for (int c = 0; c < nchunks; c++) {
    ln1_win_kernel<<<MW, 256, 0, stream>>>(x, ln1_g, ln1_b, win_c, c * MW);
    mgemm_kernel<0><<<dim3(18, gy), 256, 0, stream>>>(
        win_c, wqkvT, b_qkv, MW, 2304, 768, nullptr, nullptr, nullptr, 0,
        qb_c, kb_c, vT_c);
    rel_kernel<<<NW * 12, 256, 0, stream>>>(qb_c, rph, rpw, relh_c, relw_c);
    sgemm64_kernel<0><<<dim3(4, NW * 12), 256, 0, stream>>>(
        qb_c, kb_c, 64, 196, relh_c, relw_c, pe_c, nullptr);
    sgemm64_kernel<1><<<dim3(1, NW * 12), 256, 0, stream>>>(
        vT_c, pe_c, 256, 64, nullptr, nullptr, nullptr, win_c);
    mgemm_kernel<1><<<dim3(6, gy), 256, 0, stream>>>(
        win_c, wprojT, b_proj, MW, 768, 768, out, nullptr, x, c * MW,
        nullptr, nullptr, nullptr);  // x1 lives in d_out
  }
  for (int r0 = 0; r0 < 16384; r0 += R) {
    ln2_kernel<<<R, 256, 0, stream>>>(out + (size_t)r0 * 768, ln2_g, ln2_b, y_c);
    mgemm_kernel<2><<<dim3(24, R / 128), 256, 0, stream>>>(
        y_c, wfc1T, b_fc1, R, 3072, 768, nullptr, h_c, nullptr, 0,
        nullptr, nullptr, nullptr);
    mgemm_kernel<3><<<dim3(6, R / 128), 256, 0, stream>>>(
        h_c, wfc2T, b_fc2, R, 768, 3072, out + (size_t)r0 * 768, nullptr,
        out + (size_t)r0 * 768, 0, nullptr, nullptr, nullptr);
  }
}